// Round 12
// baseline (482.058 us; speedup 1.0000x reference)
//
#include <hip/hip_runtime.h>
#include <cstddef>

#define NUM_BLOCKS 8
#define BLK 512
#define D_IN 2048
#define NROWS 8192
#define NBUCKETS (NUM_BLOCKS * BLK) /* 4096 */
#define CAP 32                      /* int-ELL padded capacity (tail path) */
#define ROWS_PER_WG 8
#define THREADS 512
#define SENT 4096                   /* sentinel entry -> zeroed LDS row 2048 */

typedef float    v4f __attribute__((ext_vector_type(4)));
typedef unsigned v4u __attribute__((ext_vector_type(4)));

// ---------------- index build (unchanged, proven) ----------------
__global__ __launch_bounds__(256) void cs_build_index(
    const int* __restrict__ i_hash, const float* __restrict__ s_hash,
    int* __restrict__ nchunks, int* __restrict__ entries,
    unsigned short* __restrict__ entries16)
{
    const int gid  = blockIdx.x * blockDim.x + threadIdx.x;
    const int wave = gid >> 6;
    const int lane = threadIdx.x & 63;
    if (wave >= NBUCKETS) return;
    const int b = wave >> 9;
    const int k = wave & (BLK - 1);
    const int*   ih = i_hash + b * D_IN;
    const float* sr = s_hash + b * D_IN;
    int* erow = entries + wave * CAP;
    unsigned short* e16 = entries16 + wave * 8;
    int cnt = 0;
    for (int d0 = 0; d0 < D_IN; d0 += 64) {
        const int d = d0 + lane;
        const bool m = (ih[d] == k);
        const unsigned long long mask = __ballot(m);
        if (m) {
            const int pos = cnt + __popcll(mask & ((1ull << lane) - 1ull));
            const int ent = (d << 1) | ((sr[d] < 0.0f) ? 1 : 0);
            if (pos < CAP) erow[pos] = ent;
            if (pos < 8)   e16[pos]  = (unsigned short)ent;
        }
        cnt += (int)__popcll(mask);
    }
    if (cnt > CAP) cnt = CAP;
    int nch = (cnt + 3) >> 2;
    if (nch == 0) nch = 1;
    if (lane >= cnt) {
        if (lane < 8)       e16[lane]  = (unsigned short)SENT;
        if (lane < nch * 4) erow[lane] = SENT;
    }
    if (lane == 0) nchunks[wave] = nch;
}

// ---------------- PROBE A: pure store pattern, x4 passes ----------------
// Writes zeros over the full output with the gather's exact NT float4
// pattern, 4 complete passes (grid 4x). dur/4 = pure store-phase time.
// Runs BEFORE the real gather, which overwrites everything -> correct.
__global__ __launch_bounds__(THREADS) void probe_store(float* __restrict__ out)
{
    const int tid  = threadIdx.x;
    const int row0 = (blockIdx.x & 1023) * ROWS_PER_WG;
    const v4f z = {0.f, 0.f, 0.f, 0.f};
#pragma unroll
    for (int g = 0; g < 2; ++g) {
        const int col4 = tid + 512 * g;
#pragma unroll
        for (int rr = 0; rr < 8; ++rr)
            __builtin_nontemporal_store(
                z, (v4f*)(out + (size_t)(row0 + rr) * NBUCKETS + 4 * col4));
    }
}

// ---------------- PROBE B: stage + compute x4, no stores ----------------
// R8's exact staging and compute; stores replaced by folding acc into a
// sink. Compute repeated 4x with a memory clobber between reps (forces
// LDS re-reads). (dur - stage)/4 = compute-phase time. Guard store can
// essentially never fire, and even if it did, the real gather overwrites.
__global__ __launch_bounds__(THREADS, 4) void probe_compute(
    const float* __restrict__ x, const int* __restrict__ nchunks,
    const int* __restrict__ entries, const v4u* __restrict__ entries16,
    float* __restrict__ out)
{
    __shared__ v4u xs4[D_IN + 1];
    const int tid  = threadIdx.x;
    const int row0 = (blockIdx.x & 1023) * ROWS_PER_WG;

    v4u e8[8];
    int nch[8];
#pragma unroll
    for (int g = 0; g < 2; ++g)
#pragma unroll
        for (int q = 0; q < 4; ++q) {
            const int j = 4 * (tid + 512 * g) + q;
            e8[g * 4 + q]  = entries16[j];
            nch[g * 4 + q] = nchunks[j];
        }

    if (tid == 0) xs4[D_IN] = (v4u){0u, 0u, 0u, 0u};

    const size_t b0 = (size_t)row0 * D_IN;
#pragma unroll
    for (int i = 0; i < 4; ++i) {
        const int d = tid + i * THREADS;
        unsigned r[8];
#pragma unroll
        for (int rr = 0; rr < 8; ++rr) {
            const unsigned u = __float_as_uint(x[b0 + (size_t)rr * D_IN + d]);
            r[rr] = (u + 0x7fffu + ((u >> 16) & 1u)) >> 16;
        }
        v4u w;
        w.x = r[0] | (r[1] << 16);
        w.y = r[2] | (r[3] << 16);
        w.z = r[4] | (r[5] << 16);
        w.w = r[6] | (r[7] << 16);
        xs4[d] = w;
    }
    __syncthreads();

#define ASF __uint_as_float
#define PE(e, A)                                                          \
    do {                                                                  \
        const unsigned ue = (unsigned)(e);                                \
        const unsigned sm = (ue & 1u) ? 0x80008000u : 0u;                 \
        const v4u w = xs4[ue >> 1];                                       \
        const unsigned w0 = w.x ^ sm, w1 = w.y ^ sm;                      \
        const unsigned w2 = w.z ^ sm, w3 = w.w ^ sm;                      \
        A[0] += ASF(w0 << 16); A[1] += ASF(w0 & 0xffff0000u);             \
        A[2] += ASF(w1 << 16); A[3] += ASF(w1 & 0xffff0000u);             \
        A[4] += ASF(w2 << 16); A[5] += ASF(w2 & 0xffff0000u);             \
        A[6] += ASF(w3 << 16); A[7] += ASF(w3 & 0xffff0000u);             \
    } while (0)

    float sink = 0.0f;
#pragma unroll 1
    for (int rep = 0; rep < 4; ++rep) {
        asm volatile("" ::: "memory");   // force LDS re-reads each rep
#pragma unroll
        for (int g = 0; g < 2; ++g) {
            const int col4 = tid + 512 * g;
            float acc[4][8];
#pragma unroll
            for (int q = 0; q < 4; ++q)
#pragma unroll
                for (int rr = 0; rr < 8; ++rr) acc[q][rr] = 0.0f;
#pragma unroll
            for (int q = 0; q < 4; ++q) {
                const v4u ew = e8[g * 4 + q];
                PE(ew.x & 0xffffu, acc[q]); PE(ew.x >> 16, acc[q]);
                PE(ew.y & 0xffffu, acc[q]); PE(ew.y >> 16, acc[q]);
                PE(ew.z & 0xffffu, acc[q]); PE(ew.z >> 16, acc[q]);
                PE(ew.w & 0xffffu, acc[q]);
                PE(ew.w >> 16, acc[q]);
                const int n = nch[g * 4 + q];
                if (n > 2) {
                    const int j = 4 * col4 + q;
                    const int4* __restrict__ ep =
                        (const int4*)(entries + j * CAP);
#pragma unroll 1
                    for (int c = 2; c < n; ++c) {
                        const int4 cc = ep[c];
                        PE(cc.x, acc[q]); PE(cc.y, acc[q]);
                        PE(cc.z, acc[q]); PE(cc.w, acc[q]);
                    }
                }
            }
#pragma unroll
            for (int q = 0; q < 4; ++q)
#pragma unroll
                for (int rr = 0; rr < 8; ++rr) sink += acc[q][rr];
        }
    }
    // Guard store: specific bit pattern, astronomically improbable; even
    // if hit, cs_gather overwrites out[0] afterwards (still deterministic).
    if (__float_as_uint(sink) == 0x7f3b1a2cu) out[0] = sink;
#undef PE
#undef ASF
}

// ---------------- real gather: R8 exact (best known, 55.6 us) ----------------
__global__ __launch_bounds__(THREADS, 4) void cs_gather(
    const float* __restrict__ x, const int* __restrict__ nchunks,
    const int* __restrict__ entries, const v4u* __restrict__ entries16,
    float* __restrict__ out)
{
    __shared__ v4u xs4[D_IN + 1];   // 32784 B; row d = 8 bf16 (rows 0..7)
    const int tid  = threadIdx.x;
    const int row0 = blockIdx.x * ROWS_PER_WG;

    v4u e8[8];
    int nch[8];
#pragma unroll
    for (int g = 0; g < 2; ++g)
#pragma unroll
        for (int q = 0; q < 4; ++q) {
            const int j = 4 * (tid + 512 * g) + q;
            e8[g * 4 + q]  = entries16[j];
            nch[g * 4 + q] = nchunks[j];
        }

    if (tid == 0) xs4[D_IN] = (v4u){0u, 0u, 0u, 0u};  // sentinel row

    const size_t b0 = (size_t)row0 * D_IN;
#pragma unroll
    for (int i = 0; i < 4; ++i) {
        const int d = tid + i * THREADS;
        unsigned r[8];
#pragma unroll
        for (int rr = 0; rr < 8; ++rr) {
            const unsigned u = __float_as_uint(x[b0 + (size_t)rr * D_IN + d]);
            r[rr] = (u + 0x7fffu + ((u >> 16) & 1u)) >> 16;  // RNE bf16
        }
        v4u w;
        w.x = r[0] | (r[1] << 16);
        w.y = r[2] | (r[3] << 16);
        w.z = r[4] | (r[5] << 16);
        w.w = r[6] | (r[7] << 16);
        xs4[d] = w;
    }
    __syncthreads();

    const float scale = 0.35355339059327373f; // 1/sqrt(8)
#define ASF __uint_as_float
#define PE(e, A)                                                          \
    do {                                                                  \
        const unsigned ue = (unsigned)(e);                                \
        const unsigned sm = (ue & 1u) ? 0x80008000u : 0u;                 \
        const v4u w = xs4[ue >> 1];                                       \
        const unsigned w0 = w.x ^ sm, w1 = w.y ^ sm;                      \
        const unsigned w2 = w.z ^ sm, w3 = w.w ^ sm;                      \
        A[0] += ASF(w0 << 16); A[1] += ASF(w0 & 0xffff0000u);             \
        A[2] += ASF(w1 << 16); A[3] += ASF(w1 & 0xffff0000u);             \
        A[4] += ASF(w2 << 16); A[5] += ASF(w2 & 0xffff0000u);             \
        A[6] += ASF(w3 << 16); A[7] += ASF(w3 & 0xffff0000u);             \
    } while (0)

#pragma unroll
    for (int g = 0; g < 2; ++g) {
        const int col4 = tid + 512 * g;
        float acc[4][8];
#pragma unroll
        for (int q = 0; q < 4; ++q)
#pragma unroll
            for (int rr = 0; rr < 8; ++rr) acc[q][rr] = 0.0f;

#pragma unroll
        for (int q = 0; q < 4; ++q) {
            const v4u ew = e8[g * 4 + q];
            PE(ew.x & 0xffffu, acc[q]); PE(ew.x >> 16, acc[q]);
            PE(ew.y & 0xffffu, acc[q]); PE(ew.y >> 16, acc[q]);
            PE(ew.z & 0xffffu, acc[q]); PE(ew.z >> 16, acc[q]);
            PE(ew.w & 0xffffu, acc[q]);
            PE(ew.w >> 16, acc[q]);
            const int n = nch[g * 4 + q];
            if (n > 2) {
                const int j = 4 * col4 + q;
                const int4* __restrict__ ep = (const int4*)(entries + j * CAP);
#pragma unroll 1
                for (int c = 2; c < n; ++c) {
                    const int4 cc = ep[c];
                    PE(cc.x, acc[q]); PE(cc.y, acc[q]);
                    PE(cc.z, acc[q]); PE(cc.w, acc[q]);
                }
            }
        }
#pragma unroll
        for (int rr = 0; rr < 8; ++rr) {
            v4f v = { acc[0][rr] * scale, acc[1][rr] * scale,
                      acc[2][rr] * scale, acc[3][rr] * scale };
            __builtin_nontemporal_store(
                v, (v4f*)(out + (size_t)(row0 + rr) * NBUCKETS + 4 * col4));
        }
    }
#undef PE
#undef ASF
}

extern "C" void kernel_launch(void* const* d_in, const int* in_sizes, int n_in,
                              void* d_out, int out_size, void* d_ws, size_t ws_size,
                              hipStream_t stream)
{
    const float* x      = (const float*)d_in[0];
    const float* s_hash = (const float*)d_in[1];
    const int*   i_hash = (const int*)d_in[2];
    float* out = (float*)d_out;

    int* nchunks = (int*)d_ws;
    int* entries = nchunks + NBUCKETS;
    unsigned short* entries16 = (unsigned short*)(entries + NBUCKETS * CAP);

    cs_build_index<<<(NBUCKETS * 64) / 256, 256, 0, stream>>>(
        i_hash, s_hash, nchunks, entries, entries16);
    // diagnostic probes (before gather; gather overwrites d_out fully)
    probe_store<<<4096, THREADS, 0, stream>>>(out);
    probe_compute<<<1024, THREADS, 0, stream>>>(
        x, nchunks, entries, (const v4u*)entries16, out);
    // real gather (R8 structure)
    cs_gather<<<NROWS / ROWS_PER_WG, THREADS, 0, stream>>>(
        x, nchunks, entries, (const v4u*)entries16, out);
}

// Round 13
// 288.051 us; speedup vs baseline: 1.6735x; 1.6735x over previous
//
#include <hip/hip_runtime.h>
#include <cstddef>

#define NUM_BLOCKS 8
#define BLK 512
#define D_IN 2048
#define NROWS 8192
#define NBUCKETS (NUM_BLOCKS * BLK) /* 4096 */
#define CAP 32
#define ROWS_PER_WG 8
#define THREADS 512
#define SENT 4096

typedef float    v4f __attribute__((ext_vector_type(4)));
typedef unsigned v4u __attribute__((ext_vector_type(4)));

// ---------------- index build (unchanged, proven) ----------------
__global__ __launch_bounds__(256) void cs_build_index(
    const int* __restrict__ i_hash, const float* __restrict__ s_hash,
    int* __restrict__ nchunks, int* __restrict__ entries,
    unsigned short* __restrict__ entries16)
{
    const int gid  = blockIdx.x * blockDim.x + threadIdx.x;
    const int wave = gid >> 6;
    const int lane = threadIdx.x & 63;
    if (wave >= NBUCKETS) return;
    const int b = wave >> 9;
    const int k = wave & (BLK - 1);
    const int*   ih = i_hash + b * D_IN;
    const float* sr = s_hash + b * D_IN;
    int* erow = entries + wave * CAP;
    unsigned short* e16 = entries16 + wave * 8;
    int cnt = 0;
    for (int d0 = 0; d0 < D_IN; d0 += 64) {
        const int d = d0 + lane;
        const bool m = (ih[d] == k);
        const unsigned long long mask = __ballot(m);
        if (m) {
            const int pos = cnt + __popcll(mask & ((1ull << lane) - 1ull));
            const int ent = (d << 1) | ((sr[d] < 0.0f) ? 1 : 0);
            if (pos < CAP) erow[pos] = ent;
            if (pos < 8)   e16[pos]  = (unsigned short)ent;
        }
        cnt += (int)__popcll(mask);
    }
    if (cnt > CAP) cnt = CAP;
    int nch = (cnt + 3) >> 2;
    if (nch == 0) nch = 1;
    if (lane >= cnt) {
        if (lane < 8)       e16[lane]  = (unsigned short)SENT;
        if (lane < nch * 4) erow[lane] = SENT;
    }
    if (lane == 0) nchunks[wave] = nch;
}

// ---- PROBE A: exact read pattern + exact NT store pattern, no compute ----
// grid 4096 = 4 full passes. dur/4 = memory-system cost of the gather's
// access pattern (the mixed-traffic ceiling). Values stored derive from
// the loads (DCE-proof). cs_gather runs after and overwrites everything.
__global__ __launch_bounds__(THREADS) void probe_copy(
    const float* __restrict__ x, float* __restrict__ out)
{
    const int tid  = threadIdx.x;
    const int row0 = (blockIdx.x & 1023) * ROWS_PER_WG;
    const size_t b0 = (size_t)row0 * D_IN;
    float v[4][8];   // exact staging reads: 32 dwords/thread
#pragma unroll
    for (int i = 0; i < 4; ++i) {
        const int d = tid + i * THREADS;
#pragma unroll
        for (int rr = 0; rr < 8; ++rr)
            v[i][rr] = x[b0 + (size_t)rr * D_IN + d];
    }
#pragma unroll
    for (int g = 0; g < 2; ++g) {
        const int col4 = tid + 512 * g;   // exact gather store pattern
#pragma unroll
        for (int rr = 0; rr < 8; ++rr) {
            v4f w = { v[0][rr], v[1][rr], v[2][rr], v[3][rr] };
            __builtin_nontemporal_store(
                w, (v4f*)(out + (size_t)(row0 + rr) * NBUCKETS + 4 * col4));
        }
    }
}

// ---- PROBE B: exact R8 stage+compute, stores -> fold (no rep loop) ----
// grid 4096 = 4 passes, each WG identical register profile to cs_gather.
// WRITE_SIZE ~ 0 is the no-spill check. dur/4 = stage+compute time.
__global__ __launch_bounds__(THREADS, 4) void probe_sc(
    const float* __restrict__ x, const int* __restrict__ nchunks,
    const int* __restrict__ entries, const v4u* __restrict__ entries16,
    float* __restrict__ out)
{
    __shared__ v4u xs4[D_IN + 1];
    const int tid  = threadIdx.x;
    const int row0 = (blockIdx.x & 1023) * ROWS_PER_WG;

    v4u e8[8];
    int nch[8];
#pragma unroll
    for (int g = 0; g < 2; ++g)
#pragma unroll
        for (int q = 0; q < 4; ++q) {
            const int j = 4 * (tid + 512 * g) + q;
            e8[g * 4 + q]  = entries16[j];
            nch[g * 4 + q] = nchunks[j];
        }
    if (tid == 0) xs4[D_IN] = (v4u){0u, 0u, 0u, 0u};

    const size_t b0 = (size_t)row0 * D_IN;
#pragma unroll
    for (int i = 0; i < 4; ++i) {
        const int d = tid + i * THREADS;
        unsigned r[8];
#pragma unroll
        for (int rr = 0; rr < 8; ++rr) {
            const unsigned u = __float_as_uint(x[b0 + (size_t)rr * D_IN + d]);
            r[rr] = (u + 0x7fffu + ((u >> 16) & 1u)) >> 16;
        }
        v4u w;
        w.x = r[0] | (r[1] << 16); w.y = r[2] | (r[3] << 16);
        w.z = r[4] | (r[5] << 16); w.w = r[6] | (r[7] << 16);
        xs4[d] = w;
    }
    __syncthreads();

#define ASF __uint_as_float
#define PE(e, A)                                                          \
    do {                                                                  \
        const unsigned ue = (unsigned)(e);                                \
        const unsigned sm = (ue & 1u) ? 0x80008000u : 0u;                 \
        const v4u w = xs4[ue >> 1];                                       \
        const unsigned w0 = w.x ^ sm, w1 = w.y ^ sm;                      \
        const unsigned w2 = w.z ^ sm, w3 = w.w ^ sm;                      \
        A[0] += ASF(w0 << 16); A[1] += ASF(w0 & 0xffff0000u);             \
        A[2] += ASF(w1 << 16); A[3] += ASF(w1 & 0xffff0000u);             \
        A[4] += ASF(w2 << 16); A[5] += ASF(w2 & 0xffff0000u);             \
        A[6] += ASF(w3 << 16); A[7] += ASF(w3 & 0xffff0000u);             \
    } while (0)

    float sink = 0.0f;
#pragma unroll
    for (int g = 0; g < 2; ++g) {
        const int col4 = tid + 512 * g;
        float acc[4][8];
#pragma unroll
        for (int q = 0; q < 4; ++q)
#pragma unroll
            for (int rr = 0; rr < 8; ++rr) acc[q][rr] = 0.0f;
#pragma unroll
        for (int q = 0; q < 4; ++q) {
            const v4u ew = e8[g * 4 + q];
            PE(ew.x & 0xffffu, acc[q]); PE(ew.x >> 16, acc[q]);
            PE(ew.y & 0xffffu, acc[q]); PE(ew.y >> 16, acc[q]);
            PE(ew.z & 0xffffu, acc[q]); PE(ew.z >> 16, acc[q]);
            PE(ew.w & 0xffffu, acc[q]);
            PE(ew.w >> 16, acc[q]);
            const int n = nch[g * 4 + q];
            if (n > 2) {
                const int j = 4 * col4 + q;
                const int4* __restrict__ ep = (const int4*)(entries + j * CAP);
#pragma unroll 1
                for (int c = 2; c < n; ++c) {
                    const int4 cc = ep[c];
                    PE(cc.x, acc[q]); PE(cc.y, acc[q]);
                    PE(cc.z, acc[q]); PE(cc.w, acc[q]);
                }
            }
        }
#pragma unroll
        for (int q = 0; q < 4; ++q)
#pragma unroll
            for (int rr = 0; rr < 8; ++rr) sink += acc[q][rr];
    }
    if (__float_as_uint(sink) == 0x7f3b1a2cu) out[0] = sink; // ~never; overwritten anyway
#undef PE
#undef ASF
}

// ---------------- real gather: R8 exact ----------------
__global__ __launch_bounds__(THREADS, 4) void cs_gather(
    const float* __restrict__ x, const int* __restrict__ nchunks,
    const int* __restrict__ entries, const v4u* __restrict__ entries16,
    float* __restrict__ out)
{
    __shared__ v4u xs4[D_IN + 1];
    const int tid  = threadIdx.x;
    const int row0 = blockIdx.x * ROWS_PER_WG;

    v4u e8[8];
    int nch[8];
#pragma unroll
    for (int g = 0; g < 2; ++g)
#pragma unroll
        for (int q = 0; q < 4; ++q) {
            const int j = 4 * (tid + 512 * g) + q;
            e8[g * 4 + q]  = entries16[j];
            nch[g * 4 + q] = nchunks[j];
        }
    if (tid == 0) xs4[D_IN] = (v4u){0u, 0u, 0u, 0u};

    const size_t b0 = (size_t)row0 * D_IN;
#pragma unroll
    for (int i = 0; i < 4; ++i) {
        const int d = tid + i * THREADS;
        unsigned r[8];
#pragma unroll
        for (int rr = 0; rr < 8; ++rr) {
            const unsigned u = __float_as_uint(x[b0 + (size_t)rr * D_IN + d]);
            r[rr] = (u + 0x7fffu + ((u >> 16) & 1u)) >> 16;  // RNE bf16
        }
        v4u w;
        w.x = r[0] | (r[1] << 16); w.y = r[2] | (r[3] << 16);
        w.z = r[4] | (r[5] << 16); w.w = r[6] | (r[7] << 16);
        xs4[d] = w;
    }
    __syncthreads();

    const float scale = 0.35355339059327373f; // 1/sqrt(8)
#define ASF __uint_as_float
#define PE(e, A)                                                          \
    do {                                                                  \
        const unsigned ue = (unsigned)(e);                                \
        const unsigned sm = (ue & 1u) ? 0x80008000u : 0u;                 \
        const v4u w = xs4[ue >> 1];                                       \
        const unsigned w0 = w.x ^ sm, w1 = w.y ^ sm;                      \
        const unsigned w2 = w.z ^ sm, w3 = w.w ^ sm;                      \
        A[0] += ASF(w0 << 16); A[1] += ASF(w0 & 0xffff0000u);             \
        A[2] += ASF(w1 << 16); A[3] += ASF(w1 & 0xffff0000u);             \
        A[4] += ASF(w2 << 16); A[5] += ASF(w2 & 0xffff0000u);             \
        A[6] += ASF(w3 << 16); A[7] += ASF(w3 & 0xffff0000u);             \
    } while (0)

#pragma unroll
    for (int g = 0; g < 2; ++g) {
        const int col4 = tid + 512 * g;
        float acc[4][8];
#pragma unroll
        for (int q = 0; q < 4; ++q)
#pragma unroll
            for (int rr = 0; rr < 8; ++rr) acc[q][rr] = 0.0f;

#pragma unroll
        for (int q = 0; q < 4; ++q) {
            const v4u ew = e8[g * 4 + q];
            PE(ew.x & 0xffffu, acc[q]); PE(ew.x >> 16, acc[q]);
            PE(ew.y & 0xffffu, acc[q]); PE(ew.y >> 16, acc[q]);
            PE(ew.z & 0xffffu, acc[q]); PE(ew.z >> 16, acc[q]);
            PE(ew.w & 0xffffu, acc[q]);
            PE(ew.w >> 16, acc[q]);
            const int n = nch[g * 4 + q];
            if (n > 2) {
                const int j = 4 * col4 + q;
                const int4* __restrict__ ep = (const int4*)(entries + j * CAP);
#pragma unroll 1
                for (int c = 2; c < n; ++c) {
                    const int4 cc = ep[c];
                    PE(cc.x, acc[q]); PE(cc.y, acc[q]);
                    PE(cc.z, acc[q]); PE(cc.w, acc[q]);
                }
            }
        }
#pragma unroll
        for (int rr = 0; rr < 8; ++rr) {
            v4f v = { acc[0][rr] * scale, acc[1][rr] * scale,
                      acc[2][rr] * scale, acc[3][rr] * scale };
            __builtin_nontemporal_store(
                v, (v4f*)(out + (size_t)(row0 + rr) * NBUCKETS + 4 * col4));
        }
    }
#undef PE
#undef ASF
}

extern "C" void kernel_launch(void* const* d_in, const int* in_sizes, int n_in,
                              void* d_out, int out_size, void* d_ws, size_t ws_size,
                              hipStream_t stream)
{
    const float* x      = (const float*)d_in[0];
    const float* s_hash = (const float*)d_in[1];
    const int*   i_hash = (const int*)d_in[2];
    float* out = (float*)d_out;

    int* nchunks = (int*)d_ws;
    int* entries = nchunks + NBUCKETS;
    unsigned short* entries16 = (unsigned short*)(entries + NBUCKETS * CAP);

    cs_build_index<<<(NBUCKETS * 64) / 256, 256, 0, stream>>>(
        i_hash, s_hash, nchunks, entries, entries16);
    // clean diagnostic probes (before gather; gather overwrites d_out)
    probe_copy<<<4096, THREADS, 0, stream>>>(x, out);
    probe_sc<<<4096, THREADS, 0, stream>>>(
        x, nchunks, entries, (const v4u*)entries16, out);
    // real gather (R8 structure)
    cs_gather<<<NROWS / ROWS_PER_WG, THREADS, 0, stream>>>(
        x, nchunks, entries, (const v4u*)entries16, out);
}

// Round 14
// 55.239 us; speedup vs baseline: 8.7268x; 5.2146x over previous
//
#include <hip/hip_runtime.h>
#include <cstddef>

#define NUM_BLOCKS 8
#define BLK 512
#define D_IN 2048
#define NROWS 8192
#define NBUCKETS (NUM_BLOCKS * BLK) /* 4096 */
#define CAP 32
#define ROWS_PER_WG 8
#define THREADS 512
#define SENT 4096

typedef float    v2f __attribute__((ext_vector_type(2)));
typedef float    v4f __attribute__((ext_vector_type(4)));
typedef unsigned v4u __attribute__((ext_vector_type(4)));

// ---------------- index build (unchanged, proven) ----------------
__global__ __launch_bounds__(256) void cs_build_index(
    const int* __restrict__ i_hash, const float* __restrict__ s_hash,
    int* __restrict__ nchunks, int* __restrict__ entries,
    unsigned short* __restrict__ entries16)
{
    const int gid  = blockIdx.x * blockDim.x + threadIdx.x;
    const int wave = gid >> 6;
    const int lane = threadIdx.x & 63;
    if (wave >= NBUCKETS) return;
    const int b = wave >> 9;
    const int k = wave & (BLK - 1);
    const int*   ih = i_hash + b * D_IN;
    const float* sr = s_hash + b * D_IN;
    int* erow = entries + wave * CAP;
    unsigned short* e16 = entries16 + wave * 8;
    int cnt = 0;
    for (int d0 = 0; d0 < D_IN; d0 += 64) {
        const int d = d0 + lane;
        const bool m = (ih[d] == k);
        const unsigned long long mask = __ballot(m);
        if (m) {
            const int pos = cnt + __popcll(mask & ((1ull << lane) - 1ull));
            const int ent = (d << 1) | ((sr[d] < 0.0f) ? 1 : 0);
            if (pos < CAP) erow[pos] = ent;
            if (pos < 8)   e16[pos]  = (unsigned short)ent;
        }
        cnt += (int)__popcll(mask);
    }
    if (cnt > CAP) cnt = CAP;
    int nch = (cnt + 3) >> 2;
    if (nch == 0) nch = 1;
    if (lane >= cnt) {
        if (lane < 8)       e16[lane]  = (unsigned short)SENT;
        if (lane < nch * 4) erow[lane] = SENT;
    }
    if (lane == 0) nchunks[wave] = nch;
}

// Gather (R8 inner structure; change: stores spread into 4 clusters with
// wave-staggered group order). Thread t owns 8 buckets as 4 groups of 2:
// group g -> buckets 2*(t+512g)+{0,1}. Wave w processes groups in order
// (w&3), (w&3)+1, ... so the 8 waves of a WG occupy 4 different phase
// offsets: NT dwordx2 stores issue quasi-continuously from ~12% of the
// kernel instead of two synchronized bursts (R13 probes: gather ~= memory
// time + compute time SUMMED; this overlaps them). Descriptor registers
// are loaded into wave-rotated SLOTS so all register indexing stays
// static (no scratch). bf16 transposed tile (one b128 read serves 8
// rows); sentinel row 2048 is zeros; fmaf(+-1) PE form.
__global__ __launch_bounds__(THREADS, 4) void cs_gather(
    const float* __restrict__ x, const int* __restrict__ nchunks,
    const int* __restrict__ entries, const v4u* __restrict__ entries16,
    float* __restrict__ out)
{
    __shared__ v4u xs4[D_IN + 1];   // 32784 B; row d = 8 bf16 (rows 0..7)
    const int tid  = threadIdx.x;
    const int wv   = tid >> 6;      // wave id 0..7
    const int row0 = blockIdx.x * ROWS_PER_WG;

    // Descriptors into wave-rotated slots (slot s holds group (s+wv)&3).
    v4u e8[8];
    int nch8[8];
#pragma unroll
    for (int s = 0; s < 4; ++s) {
        const int g = (s + wv) & 3;
#pragma unroll
        for (int q = 0; q < 2; ++q) {
            const int j = 2 * (tid + 512 * g) + q;
            e8[s * 2 + q]  = entries16[j];
            nch8[s * 2 + q] = nchunks[j];
        }
    }

    if (tid == 0) xs4[D_IN] = (v4u){0u, 0u, 0u, 0u};  // sentinel row

    // Stage transposed bf16 (R8 exact): 8 coalesced dword loads -> RNE
    // pack -> 1 ds_write_b128 per owned d.
    const size_t b0 = (size_t)row0 * D_IN;
#pragma unroll
    for (int i = 0; i < 4; ++i) {
        const int d = tid + i * THREADS;
        unsigned r[8];
#pragma unroll
        for (int rr = 0; rr < 8; ++rr) {
            const unsigned u = __float_as_uint(x[b0 + (size_t)rr * D_IN + d]);
            r[rr] = (u + 0x7fffu + ((u >> 16) & 1u)) >> 16;  // RNE bf16
        }
        v4u w;
        w.x = r[0] | (r[1] << 16); w.y = r[2] | (r[3] << 16);
        w.z = r[4] | (r[5] << 16); w.w = r[6] | (r[7] << 16);
        xs4[d] = w;
    }
    __syncthreads();

    const float scale = 0.35355339059327373f; // 1/sqrt(8)
#define ASF __uint_as_float

    // One b128 read; sign via fmaf(+-1); sentinel -> zeros row (exact noop).
#define PE(e, A)                                                          \
    do {                                                                  \
        const unsigned ue = (unsigned)(e);                                \
        const float sg = (ue & 1u) ? -1.0f : 1.0f;                        \
        const v4u w = xs4[ue >> 1];                                       \
        A[0] = fmaf(sg, ASF(w.x << 16),         A[0]);                    \
        A[1] = fmaf(sg, ASF(w.x & 0xffff0000u), A[1]);                    \
        A[2] = fmaf(sg, ASF(w.y << 16),         A[2]);                    \
        A[3] = fmaf(sg, ASF(w.y & 0xffff0000u), A[3]);                    \
        A[4] = fmaf(sg, ASF(w.z << 16),         A[4]);                    \
        A[5] = fmaf(sg, ASF(w.z & 0xffff0000u), A[5]);                    \
        A[6] = fmaf(sg, ASF(w.w << 16),         A[6]);                    \
        A[7] = fmaf(sg, ASF(w.w & 0xffff0000u), A[7]);                    \
    } while (0)

#pragma unroll
    for (int s = 0; s < 4; ++s) {           // static slot loop
        const int g    = (s + wv) & 3;      // runtime group (address only)
        const int col2 = tid + 512 * g;
        float acc[2][8];
#pragma unroll
        for (int q = 0; q < 2; ++q)
#pragma unroll
            for (int rr = 0; rr < 8; ++rr) acc[q][rr] = 0.0f;

#pragma unroll
        for (int q = 0; q < 2; ++q) {
            const v4u ew = e8[s * 2 + q];
            PE(ew.x & 0xffffu, acc[q]); PE(ew.x >> 16, acc[q]);
            PE(ew.y & 0xffffu, acc[q]); PE(ew.y >> 16, acc[q]);
            PE(ew.z & 0xffffu, acc[q]); PE(ew.z >> 16, acc[q]);
            PE(ew.w & 0xffffu, acc[q]);
            PE(ew.w >> 16, acc[q]);
            const int n = nch8[s * 2 + q];
            if (n > 2) {                    // rare (~2% of buckets)
                const int j = 2 * col2 + q;
                const int4* __restrict__ ep = (const int4*)(entries + j * CAP);
#pragma unroll 1
                for (int c = 2; c < n; ++c) {
                    const int4 cc = ep[c];
                    PE(cc.x, acc[q]); PE(cc.y, acc[q]);
                    PE(cc.z, acc[q]); PE(cc.w, acc[q]);
                }
            }
        }
        // Store this group's 2 buckets immediately: 8 NT dwordx2 stores.
#pragma unroll
        for (int rr = 0; rr < 8; ++rr) {
            v2f v = { acc[0][rr] * scale, acc[1][rr] * scale };
            __builtin_nontemporal_store(
                v, (v2f*)(out + (size_t)(row0 + rr) * NBUCKETS + 2 * col2));
        }
    }
#undef PE
#undef ASF
}

extern "C" void kernel_launch(void* const* d_in, const int* in_sizes, int n_in,
                              void* d_out, int out_size, void* d_ws, size_t ws_size,
                              hipStream_t stream)
{
    const float* x      = (const float*)d_in[0];
    const float* s_hash = (const float*)d_in[1];
    const int*   i_hash = (const int*)d_in[2];
    float* out = (float*)d_out;

    int* nchunks = (int*)d_ws;
    int* entries = nchunks + NBUCKETS;
    unsigned short* entries16 = (unsigned short*)(entries + NBUCKETS * CAP);

    cs_build_index<<<(NBUCKETS * 64) / 256, 256, 0, stream>>>(
        i_hash, s_hash, nchunks, entries, entries16);
    cs_gather<<<NROWS / ROWS_PER_WG, THREADS, 0, stream>>>(
        x, nchunks, entries, (const v4u*)entries16, out);
}